// Round 1
// baseline (3106.768 us; speedup 1.0000x reference)
//
#include <hip/hip_runtime.h>
#include <hip/hip_bf16.h>

// ---------------------------------------------------------------------------
// Bidirectional GRU encoder (Keras reset_after=true), B=64 S=512 U=256 V=32000
// Plan:
//   k0: repack Uf/Ub fp32 -> bf16, layout [dir][kb=32][col=768][8k] (16B/lane)
//   k1: gx GEMM: gx[dir][row][col] = emb[x[row]] @ W + b_in (+ b_rec for z,r)
//       stored bf16 in workspace (100.7 MB)
//   k2: recurrence: 128 workgroups (batch x dir), 256 threads = 1 unit each,
//       h fp32 in LDS, U streamed bf16 from L2, atomicAdd into zeroed d_out
// ws layout: [0, 768KB) packed U ; [1MB, 1MB+100.7MB) gx bf16
// Assumes: x passed as int32; ws_size >= ~102 MB.
// ---------------------------------------------------------------------------

__device__ __forceinline__ float blo(unsigned int u) { return __uint_as_float(u << 16); }
__device__ __forceinline__ float bhi(unsigned int u) { return __uint_as_float(u & 0xffff0000u); }
__device__ __forceinline__ unsigned short f2bf(float f) {
  unsigned int u = __float_as_uint(f);
  unsigned int r = (u + 0x7fffu + ((u >> 16) & 1u)) >> 16;  // RNE
  return (unsigned short)r;
}

// ---------------- k0: repack U to bf16 [2][32][768][8] ----------------------
__global__ void __launch_bounds__(256) repack_u_kernel(const float* __restrict__ Uf,
                                                       const float* __restrict__ Ub,
                                                       unsigned short* __restrict__ Up) {
  int idx = blockIdx.x * 256 + threadIdx.x;            // (dir,kb,c)
  if (idx >= 2 * 32 * 768) return;
  int c   = idx % 768;
  int kb  = (idx / 768) % 32;
  int dir = idx / (768 * 32);
  const float* U = dir ? Ub : Uf;
  unsigned short* o = Up + (size_t)idx * 8;
#pragma unroll
  for (int i = 0; i < 8; ++i) o[i] = f2bf(U[(size_t)(kb * 8 + i) * 768 + c]);
}

// ---------------- k1: gx = emb[x] @ W + bias, bf16 out ----------------------
// grid (512, 24): blockIdx.x = 64-row tile, blockIdx.y = 64-col tile (12 per dir)
__global__ void __launch_bounds__(256) gx_gemm_kernel(
    const int* __restrict__ x, const float* __restrict__ emb,
    const float* __restrict__ Wf, const float* __restrict__ Wb,
    const float* __restrict__ bf, const float* __restrict__ bb,
    unsigned short* __restrict__ gx) {
  constexpr int TM = 64, TN = 64, TK = 64;
  __shared__ float As[TK][TM + 1];
  __shared__ float Bs[TK][TN + 1];
  __shared__ int xid[TM];

  int tid = threadIdx.x;
  int r0 = blockIdx.x * TM;
  int ct = blockIdx.y;
  int dir = (ct >= 12) ? 1 : 0;
  int c0 = (ct - dir * 12) * TN;            // col within [0,768)
  const float* W  = dir ? Wb : Wf;
  const float* bv = dir ? bb : bf;

  if (tid < TM) xid[tid] = x[r0 + tid];
  __syncthreads();

  int tx = tid & 15, ty = tid >> 4;
  float acc[4][4] = {};

  for (int k0 = 0; k0 < 256; k0 += TK) {
#pragma unroll
    for (int i = 0; i < (TM * TK) / 256; ++i) {
      int l = tid + i * 256;
      int row = l >> 6, k = l & 63;                     // lanes sweep k: coalesced
      As[k][row] = emb[(size_t)xid[row] * 256 + k0 + k];
    }
#pragma unroll
    for (int i = 0; i < (TK * TN) / 256; ++i) {
      int l = tid + i * 256;
      int k = l >> 6, c = l & 63;                       // lanes sweep c: coalesced
      Bs[k][c] = W[(size_t)(k0 + k) * 768 + c0 + c];
    }
    __syncthreads();
#pragma unroll 8
    for (int kk = 0; kk < TK; ++kk) {
      float a0 = As[kk][ty * 4 + 0], a1 = As[kk][ty * 4 + 1];
      float a2 = As[kk][ty * 4 + 2], a3 = As[kk][ty * 4 + 3];
      float b0 = Bs[kk][tx * 4 + 0], b1 = Bs[kk][tx * 4 + 1];
      float b2 = Bs[kk][tx * 4 + 2], b3 = Bs[kk][tx * 4 + 3];
      acc[0][0] = fmaf(a0, b0, acc[0][0]); acc[0][1] = fmaf(a0, b1, acc[0][1]);
      acc[0][2] = fmaf(a0, b2, acc[0][2]); acc[0][3] = fmaf(a0, b3, acc[0][3]);
      acc[1][0] = fmaf(a1, b0, acc[1][0]); acc[1][1] = fmaf(a1, b1, acc[1][1]);
      acc[1][2] = fmaf(a1, b2, acc[1][2]); acc[1][3] = fmaf(a1, b3, acc[1][3]);
      acc[2][0] = fmaf(a2, b0, acc[2][0]); acc[2][1] = fmaf(a2, b1, acc[2][1]);
      acc[2][2] = fmaf(a2, b2, acc[2][2]); acc[2][3] = fmaf(a2, b3, acc[2][3]);
      acc[3][0] = fmaf(a3, b0, acc[3][0]); acc[3][1] = fmaf(a3, b1, acc[3][1]);
      acc[3][2] = fmaf(a3, b2, acc[3][2]); acc[3][3] = fmaf(a3, b3, acc[3][3]);
    }
    __syncthreads();
  }

#pragma unroll
  for (int i = 0; i < 4; ++i) {
#pragma unroll
    for (int jj = 0; jj < 4; ++jj) {
      int row = r0 + ty * 4 + i;
      int col = c0 + tx * 4 + jj;
      // b_in always; fold b_rec into z (cols 0..255) and r (256..511); h-gate
      // b_rec stays in the recurrence (it is multiplied by r there).
      float bias = bv[col] + (col < 512 ? bv[768 + col] : 0.f);
      gx[((size_t)dir * 32768 + row) * 768 + col] = f2bf(acc[i][jj] + bias);
    }
  }
}

// ---------------- k2: the recurrence ----------------------------------------
// 128 wgs: wg = dir*64 + batch. 256 threads: thread j owns unit j (cols j,
// 256+j, 512+j). h fp32 in LDS; U bf16 streamed (L2-resident, 384 KB/step).
#define FMA_U4(u, acc)                                              \
  acc = fmaf(blo(u.x), h0.x, acc); acc = fmaf(bhi(u.x), h0.y, acc); \
  acc = fmaf(blo(u.y), h0.z, acc); acc = fmaf(bhi(u.y), h0.w, acc); \
  acc = fmaf(blo(u.z), h1.x, acc); acc = fmaf(bhi(u.z), h1.y, acc); \
  acc = fmaf(blo(u.w), h1.z, acc); acc = fmaf(bhi(u.w), h1.w, acc);

__global__ void __launch_bounds__(256) gru_kernel(
    const unsigned short* __restrict__ Up,   // [2][32][768][8] bf16
    const unsigned short* __restrict__ gx,   // [2][32768][768] bf16
    const int* __restrict__ x,
    const float* __restrict__ bf, const float* __restrict__ bb,
    float* __restrict__ out) {
  int wg = blockIdx.x;
  int dir = wg >> 6, b = wg & 63;
  int j = threadIdx.x;
  __shared__ float h[256];
  h[j] = 0.f;
  __syncthreads();

  const uint4* Uq = (const uint4*)Up + (size_t)dir * (32 * 768);  // uint4 = 8 bf16
  const unsigned short* gxd = gx + ((size_t)dir * 32768 + (size_t)b * 512) * 768;
  const float brh = (dir ? bb : bf)[768 + 512 + j];   // b_rec for h-gate
  const int* xb = x + b * 512;
  float* outb = out + (size_t)b * 512 * 256;

  for (int step = 0; step < 512; ++step) {
    int t = dir ? (511 - step) : step;
    const unsigned short* g = gxd + (size_t)t * 768;
    float gxz = blo((unsigned int)g[j] << 0) , gxr, gxh;
    gxz = __uint_as_float((unsigned int)g[j] << 16);
    gxr = __uint_as_float((unsigned int)g[256 + j] << 16);
    gxh = __uint_as_float((unsigned int)g[512 + j] << 16);

    float az = 0.f, ar = 0.f, ah = 0.f;
#pragma unroll 4
    for (int kb = 0; kb < 32; ++kb) {
      const float4 h0 = *(const float4*)&h[kb * 8];
      const float4 h1 = *(const float4*)&h[kb * 8 + 4];
      uint4 uz = Uq[kb * 768 + j];
      uint4 ur = Uq[kb * 768 + 256 + j];
      uint4 uh = Uq[kb * 768 + 512 + j];
      FMA_U4(uz, az)
      FMA_U4(ur, ar)
      FMA_U4(uh, ah)
    }

    float z  = 1.f / (1.f + __expf(-(gxz + az)));
    float r  = 1.f / (1.f + __expf(-(gxr + ar)));
    float hh = tanhf(gxh + r * (ah + brh));
    float hj = h[j];
    float hn = z * hj + (1.f - z) * hh;
    if (xb[t] == 0) hn = hj;                 // masked step: carry state

    __syncthreads();                          // all reads of h done
    h[j] = hn;
    __syncthreads();                          // h visible for next step
    atomicAdd(&outb[(size_t)t * 256 + j], hn);
  }
}

// ---------------------------------------------------------------------------
extern "C" void kernel_launch(void* const* d_in, const int* in_sizes, int n_in,
                              void* d_out, int out_size, void* d_ws, size_t ws_size,
                              hipStream_t stream) {
  const int*   x   = (const int*)d_in[0];
  const float* emb = (const float*)d_in[1];
  const float* Wf  = (const float*)d_in[2];
  const float* Uf  = (const float*)d_in[3];
  const float* bf  = (const float*)d_in[4];
  const float* Wb  = (const float*)d_in[5];
  const float* Ub  = (const float*)d_in[6];
  const float* bb  = (const float*)d_in[7];
  float* out = (float*)d_out;

  unsigned short* Up  = (unsigned short*)d_ws;                       // 768 KB
  unsigned short* gxp = (unsigned short*)((char*)d_ws + (1u << 20)); // 100.7 MB

  hipMemsetAsync(d_out, 0, (size_t)out_size * sizeof(float), stream);

  repack_u_kernel<<<(2 * 32 * 768 + 255) / 256, 256, 0, stream>>>(Uf, Ub, Up);
  gx_gemm_kernel<<<dim3(512, 24), 256, 0, stream>>>(x, emb, Wf, Wb, bf, bb, gxp);
  gru_kernel<<<128, 256, 0, stream>>>(Up, gxp, x, bf, bb, out);
}

// Round 2
// 1203.965 us; speedup vs baseline: 2.5804x; 2.5804x over previous
//
#include <hip/hip_runtime.h>
#include <hip/hip_bf16.h>

// ---------------------------------------------------------------------------
// Bidirectional GRU encoder (Keras reset_after=true), B=64 S=512 U=256 V=32000
//   k1: gx GEMM: gx[dir][row][col] = emb[x[row]] @ W + b_in (+ b_rec for z,r)
//       stored bf16 in workspace (100.7 MB)  [unchanged from round 1]
//   k2: recurrence, U-in-registers version:
//       128 wgs = (dir,batch), 512 threads = 8 waves (2/SIMD).
//       Thread pair (t, t^1) owns unit j=t>>1; thread covers k-slice of 128.
//       U columns {j, 256+j, 512+j} held as fp16 pairs in 192 VGPRs.
//       Per step: 16x(ds_read_b128 of h + 12 v_dot2_f32_f16), shfl_xor(1)
//       reduce, activations, h carried fp32 in-register + fp16 in LDS.
// ws layout: [0, 100.7MB) gx bf16. Assumes x int32, ws >= 101 MB.
// ---------------------------------------------------------------------------

typedef _Float16 half2v __attribute__((ext_vector_type(2)));

__device__ __forceinline__ unsigned short f2bf(float f) {
  unsigned int u = __float_as_uint(f);
  unsigned int r = (u + 0x7fffu + ((u >> 16) & 1u)) >> 16;  // RNE
  return (unsigned short)r;
}
__device__ __forceinline__ float bf2f(unsigned short v) {
  return __uint_as_float((unsigned int)v << 16);
}
__device__ __forceinline__ unsigned int packf16(float a, float b) {
  half2v v = {(_Float16)a, (_Float16)b};
  return __builtin_bit_cast(unsigned int, v);
}
__device__ __forceinline__ float dot2(unsigned int u, unsigned int hv, float acc) {
#if __has_builtin(__builtin_amdgcn_fdot2)
  return __builtin_amdgcn_fdot2(__builtin_bit_cast(half2v, u),
                                __builtin_bit_cast(half2v, hv), acc, false);
#else
  half2v a = __builtin_bit_cast(half2v, u), b = __builtin_bit_cast(half2v, hv);
  return acc + (float)a.x * (float)b.x + (float)a.y * (float)b.y;
#endif
}

// ---------------- k1: gx = emb[x] @ W + bias, bf16 out ----------------------
__global__ void __launch_bounds__(256) gx_gemm_kernel(
    const int* __restrict__ x, const float* __restrict__ emb,
    const float* __restrict__ Wf, const float* __restrict__ Wb,
    const float* __restrict__ bf, const float* __restrict__ bb,
    unsigned short* __restrict__ gx) {
  constexpr int TM = 64, TN = 64, TK = 64;
  __shared__ float As[TK][TM + 1];
  __shared__ float Bs[TK][TN + 1];
  __shared__ int xid[TM];

  int tid = threadIdx.x;
  int r0 = blockIdx.x * TM;
  int ct = blockIdx.y;
  int dir = (ct >= 12) ? 1 : 0;
  int c0 = (ct - dir * 12) * TN;
  const float* W  = dir ? Wb : Wf;
  const float* bv = dir ? bb : bf;

  if (tid < TM) xid[tid] = x[r0 + tid];
  __syncthreads();

  int tx = tid & 15, ty = tid >> 4;
  float acc[4][4] = {};

  for (int k0 = 0; k0 < 256; k0 += TK) {
#pragma unroll
    for (int i = 0; i < (TM * TK) / 256; ++i) {
      int l = tid + i * 256;
      int row = l >> 6, k = l & 63;
      As[k][row] = emb[(size_t)xid[row] * 256 + k0 + k];
    }
#pragma unroll
    for (int i = 0; i < (TK * TN) / 256; ++i) {
      int l = tid + i * 256;
      int k = l >> 6, c = l & 63;
      Bs[k][c] = W[(size_t)(k0 + k) * 768 + c0 + c];
    }
    __syncthreads();
#pragma unroll 8
    for (int kk = 0; kk < TK; ++kk) {
      float a0 = As[kk][ty * 4 + 0], a1 = As[kk][ty * 4 + 1];
      float a2 = As[kk][ty * 4 + 2], a3 = As[kk][ty * 4 + 3];
      float b0 = Bs[kk][tx * 4 + 0], b1 = Bs[kk][tx * 4 + 1];
      float b2 = Bs[kk][tx * 4 + 2], b3 = Bs[kk][tx * 4 + 3];
      acc[0][0] = fmaf(a0, b0, acc[0][0]); acc[0][1] = fmaf(a0, b1, acc[0][1]);
      acc[0][2] = fmaf(a0, b2, acc[0][2]); acc[0][3] = fmaf(a0, b3, acc[0][3]);
      acc[1][0] = fmaf(a1, b0, acc[1][0]); acc[1][1] = fmaf(a1, b1, acc[1][1]);
      acc[1][2] = fmaf(a1, b2, acc[1][2]); acc[1][3] = fmaf(a1, b3, acc[1][3]);
      acc[2][0] = fmaf(a2, b0, acc[2][0]); acc[2][1] = fmaf(a2, b1, acc[2][1]);
      acc[2][2] = fmaf(a2, b2, acc[2][2]); acc[2][3] = fmaf(a2, b3, acc[2][3]);
      acc[3][0] = fmaf(a3, b0, acc[3][0]); acc[3][1] = fmaf(a3, b1, acc[3][1]);
      acc[3][2] = fmaf(a3, b2, acc[3][2]); acc[3][3] = fmaf(a3, b3, acc[3][3]);
    }
    __syncthreads();
  }

#pragma unroll
  for (int i = 0; i < 4; ++i) {
#pragma unroll
    for (int jj = 0; jj < 4; ++jj) {
      int row = r0 + ty * 4 + i;
      int col = c0 + tx * 4 + jj;
      float bias = bv[col] + (col < 512 ? bv[768 + col] : 0.f);
      gx[((size_t)dir * 32768 + row) * 768 + col] = f2bf(acc[i][jj] + bias);
    }
  }
}

// ---------------- k2: recurrence, U resident in VGPRs -----------------------
__global__ void __launch_bounds__(512, 2) gru_kernel(
    const float* __restrict__ Uf, const float* __restrict__ Ub,
    const unsigned short* __restrict__ gx,   // [2][32768][768] bf16
    const int* __restrict__ x,
    const float* __restrict__ bf, const float* __restrict__ bb,
    float* __restrict__ out) {
  int wg = blockIdx.x;
  int dir = wg >> 6, b = wg & 63;
  int t = threadIdx.x;
  int j = t >> 1;            // unit, 0..255
  int ks = t & 1;            // k-slice half: k in [128*ks, 128*ks+128)

  __shared__ unsigned int h_lds[128];   // 256 h values as fp16 pairs

  const float* U = dir ? Ub : Uf;
  const float brh = (dir ? bb : bf)[768 + 512 + j];  // b_rec h-gate
  const unsigned short* gxd = gx + ((size_t)dir * 32768 + (size_t)b * 512) * 768;
  const int* xb = x + b * 512;
  float* outb = out + (size_t)b * 512 * 256;

  // --- one-time: load U columns {j, 256+j, 512+j}, k-slice, fp16-packed ----
  unsigned int uz[64], ur[64], uh[64];
  {
    const float* base = U + (size_t)(ks * 128) * 768 + j;
#pragma unroll
    for (int p = 0; p < 64; ++p) {
      const float* r0 = base + (size_t)(2 * p) * 768;
      uz[p] = packf16(r0[0],   r0[768]);
      ur[p] = packf16(r0[256], r0[768 + 256]);
      uh[p] = packf16(r0[512], r0[768 + 512]);
    }
  }
  if (t < 128) h_lds[t] = 0u;
  __syncthreads();

  float hj = 0.f;   // this unit's h, fp32, carried in-register
  for (int step = 0; step < 512; ++step) {
    int tt = dir ? (511 - step) : step;
    // gx + mask loads (issued early, consumed after the dot loop)
    int xv = xb[tt];
    const unsigned short* g = gxd + (size_t)tt * 768;
    float gxz = bf2f(g[j]);
    float gxr = bf2f(g[256 + j]);
    float gxh = bf2f(g[512 + j]);

    float az = 0.f, ar = 0.f, ah = 0.f;
#pragma unroll
    for (int c = 0; c < 16; ++c) {
      uint4 hv = *(const uint4*)&h_lds[ks * 64 + c * 4];  // ds_read_b128, 2 addrs/wave
      az = dot2(uz[c * 4 + 0], hv.x, az);
      az = dot2(uz[c * 4 + 1], hv.y, az);
      az = dot2(uz[c * 4 + 2], hv.z, az);
      az = dot2(uz[c * 4 + 3], hv.w, az);
      ar = dot2(ur[c * 4 + 0], hv.x, ar);
      ar = dot2(ur[c * 4 + 1], hv.y, ar);
      ar = dot2(ur[c * 4 + 2], hv.z, ar);
      ar = dot2(ur[c * 4 + 3], hv.w, ar);
      ah = dot2(uh[c * 4 + 0], hv.x, ah);
      ah = dot2(uh[c * 4 + 1], hv.y, ah);
      ah = dot2(uh[c * 4 + 2], hv.z, ah);
      ah = dot2(uh[c * 4 + 3], hv.w, ah);
    }
    // combine the two k-halves (lane pair)
    az += __shfl_xor(az, 1);
    ar += __shfl_xor(ar, 1);
    ah += __shfl_xor(ah, 1);

    float z = 1.f / (1.f + __expf(-(gxz + az)));
    float r = 1.f / (1.f + __expf(-(gxr + ar)));
    float e2 = __expf(2.f * (gxh + r * (ah + brh)));
    float hh = (e2 - 1.f) / (e2 + 1.f);               // tanh
    float hn = z * hj + (1.f - z) * hh;
    hn = (xv == 0) ? hj : hn;                          // masked: carry state

    float hpart = __shfl_xor(hn, 2);                   // partner unit's hn
    __syncthreads();                                   // all h_lds reads done
    if ((t & 3) == 0) h_lds[t >> 2] = packf16(hn, hpart);
    __syncthreads();                                   // new h visible

    if (ks == 0) atomicAdd(&outb[(size_t)tt * 256 + j], hn);
    hj = hn;
  }
}

// ---------------------------------------------------------------------------
extern "C" void kernel_launch(void* const* d_in, const int* in_sizes, int n_in,
                              void* d_out, int out_size, void* d_ws, size_t ws_size,
                              hipStream_t stream) {
  const int*   x   = (const int*)d_in[0];
  const float* emb = (const float*)d_in[1];
  const float* Wf  = (const float*)d_in[2];
  const float* Uf  = (const float*)d_in[3];
  const float* bf  = (const float*)d_in[4];
  const float* Wb  = (const float*)d_in[5];
  const float* Ub  = (const float*)d_in[6];
  const float* bb  = (const float*)d_in[7];
  float* out = (float*)d_out;

  unsigned short* gxp = (unsigned short*)d_ws;   // 100.7 MB bf16

  hipMemsetAsync(d_out, 0, (size_t)out_size * sizeof(float), stream);

  gx_gemm_kernel<<<dim3(512, 24), 256, 0, stream>>>(x, emb, Wf, Wb, bf, bb, gxp);
  gru_kernel<<<128, 512, 0, stream>>>(Uf, Ub, gxp, x, bf, bb, out);
}

// Round 3
// 936.961 us; speedup vs baseline: 3.3158x; 1.2850x over previous
//
#include <hip/hip_runtime.h>
#include <hip/hip_bf16.h>

// ---------------------------------------------------------------------------
// Bidirectional GRU encoder (Keras reset_after=true), B=64 S=512 U=256 V=32000
//   k0: wt_prep: W [256][768] fp32 -> Wtb [dir][768][256] bf16 (transposed)
//   k1: gx_mfma: gx[dir][row][col] = emb[x[row]] @ W + b_in (+ b_rec for z,r)
//       bf16 MFMA 16x16x32, BM=BN=128 BK=32, 4 waves, XOR-swizzled LDS,
//       emb fp32 converted during A-staging. Output bf16 in ws.
//   k2: gru: 128 wgs = (dir,batch), 512 thr; U fp16-packed resident (VGPR+AGPR),
//       gx software-pipelined 1 step ahead, h double-buffered in LDS (1 barrier
//       per step), bank-conflict-free padded layout.
// ws: [0, 100.7MB) gx bf16 ; [100663296, +786432) Wtb bf16. (<= 101.5 MB)
// ---------------------------------------------------------------------------

typedef _Float16 half2v __attribute__((ext_vector_type(2)));
typedef short short8 __attribute__((ext_vector_type(8)));
typedef float f32x4 __attribute__((ext_vector_type(4)));

__device__ __forceinline__ unsigned short f2bf(float f) {
  unsigned int u = __float_as_uint(f);
  unsigned int r = (u + 0x7fffu + ((u >> 16) & 1u)) >> 16;  // RNE
  return (unsigned short)r;
}
__device__ __forceinline__ float bf2f(unsigned short v) {
  return __uint_as_float((unsigned int)v << 16);
}
__device__ __forceinline__ unsigned int packf16(float a, float b) {
  half2v v = {(_Float16)a, (_Float16)b};
  return __builtin_bit_cast(unsigned int, v);
}
__device__ __forceinline__ float dot2(unsigned int u, unsigned int hv, float acc) {
#if __has_builtin(__builtin_amdgcn_fdot2)
  return __builtin_amdgcn_fdot2(__builtin_bit_cast(half2v, u),
                                __builtin_bit_cast(half2v, hv), acc, false);
#else
  half2v a = __builtin_bit_cast(half2v, u), b = __builtin_bit_cast(half2v, hv);
  return acc + (float)a.x * (float)b.x + (float)a.y * (float)b.y;
#endif
}

// ---------------- k0: Wtb[dir][c][k] = bf16(W[k][c]) ------------------------
__global__ void __launch_bounds__(256) wt_prep_kernel(const float* __restrict__ Wf,
                                                      const float* __restrict__ Wb,
                                                      unsigned short* __restrict__ Wtb) {
  int o = blockIdx.x * 256 + threadIdx.x;
  if (o >= 2 * 768 * 256) return;
  int dir = o / (768 * 256);
  int rem = o % (768 * 256);
  int c = rem / 256, k = rem % 256;
  const float* W = dir ? Wb : Wf;
  Wtb[o] = f2bf(W[(size_t)k * 768 + c]);
}

// ---------------- k1: gx = emb[x] @ W + bias, bf16 MFMA ---------------------
// grid (256, 12): x = 128-row tile; y: dir = y>=6, c0 = (y%6)*128
__global__ void __launch_bounds__(256) gx_mfma_kernel(
    const int* __restrict__ x, const float* __restrict__ emb,
    const unsigned short* __restrict__ Wtb,
    const float* __restrict__ bfv, const float* __restrict__ bbv,
    unsigned short* __restrict__ gx) {
  __shared__ __align__(16) unsigned short As[128 * 32];  // swizzled [row][kslot^..]
  __shared__ __align__(16) unsigned short Bs[128 * 32];
  __shared__ int xid[128];

  int tid = threadIdx.x;
  int r0 = blockIdx.x * 128;
  int yt = blockIdx.y;
  int dir = (yt >= 6) ? 1 : 0;
  int c0 = (yt - dir * 6) * 128;
  const float* bv = dir ? bbv : bfv;
  const unsigned short* WtD = Wtb + (size_t)dir * 768 * 256;

  if (tid < 128) xid[tid] = x[r0 + tid];
  __syncthreads();

  int lane = tid & 63, w = tid >> 6;
  int wr = w >> 1, wc = w & 1;          // wave quadrant (2x2 of 64x64)

  f32x4 acc[4][4] = {};

  for (int ks = 0; ks < 8; ++ks) {      // K = 256 in steps of 32
#pragma unroll
    for (int i = 0; i < 2; ++i) {
      int s = tid + i * 256;            // slot 0..511: (row, kslot)
      int row = s >> 2, kslot = s & 3;
      int sw = kslot ^ ((row >> 2) & 3);
      // A: gather + fp32->bf16 convert
      const float* src = emb + (size_t)xid[row] * 256 + ks * 32 + kslot * 8;
      float4 f0 = *(const float4*)src;
      float4 f1 = *(const float4*)(src + 4);
      uint4 pa;
      pa.x = f2bf(f0.x) | ((unsigned)f2bf(f0.y) << 16);
      pa.y = f2bf(f0.z) | ((unsigned)f2bf(f0.w) << 16);
      pa.z = f2bf(f1.x) | ((unsigned)f2bf(f1.y) << 16);
      pa.w = f2bf(f1.z) | ((unsigned)f2bf(f1.w) << 16);
      *(uint4*)&As[row * 32 + sw * 8] = pa;
      // B: already bf16, pre-transposed
      uint4 pb = *(const uint4*)(WtD + (size_t)(c0 + row) * 256 + ks * 32 + kslot * 8);
      *(uint4*)&Bs[row * 32 + sw * 8] = pb;
    }
    __syncthreads();

    short8 a[4], b[4];
#pragma unroll
    for (int f = 0; f < 4; ++f) {
      int rowA = wr * 64 + f * 16 + (lane & 15);
      int swA = (lane >> 4) ^ ((rowA >> 2) & 3);
      a[f] = __builtin_bit_cast(short8, *(const uint4*)&As[rowA * 32 + swA * 8]);
      int rowB = wc * 64 + f * 16 + (lane & 15);
      int swB = (lane >> 4) ^ ((rowB >> 2) & 3);
      b[f] = __builtin_bit_cast(short8, *(const uint4*)&Bs[rowB * 32 + swB * 8]);
    }
#pragma unroll
    for (int fm = 0; fm < 4; ++fm)
#pragma unroll
      for (int fn = 0; fn < 4; ++fn)
        acc[fm][fn] = __builtin_amdgcn_mfma_f32_16x16x32_bf16(a[fm], b[fn], acc[fm][fn], 0, 0, 0);
    __syncthreads();
  }

  // epilogue: C row = (lane>>4)*4+reg (M), col = lane&15 (N)  [m89-verified]
#pragma unroll
  for (int fn = 0; fn < 4; ++fn) {
    int col = c0 + wc * 64 + fn * 16 + (lane & 15);
    float bias = bv[col] + (col < 512 ? bv[768 + col] : 0.f);
#pragma unroll
    for (int fm = 0; fm < 4; ++fm) {
      int rowb = r0 + wr * 64 + fm * 16 + (lane >> 4) * 4;
#pragma unroll
      for (int q = 0; q < 4; ++q) {
        gx[((size_t)dir * 32768 + rowb + q) * 768 + col] = f2bf(acc[fm][fn][q] + bias);
      }
    }
  }
}

// ---------------- k2: recurrence, U resident, pipelined ---------------------
__global__ void __launch_bounds__(512, 2) gru_kernel(
    const float* __restrict__ Uf, const float* __restrict__ Ub,
    const unsigned short* __restrict__ gx,   // [2][32768][768] bf16
    const int* __restrict__ x,
    const float* __restrict__ bfv, const float* __restrict__ bbv,
    float* __restrict__ out) {
  int wg = blockIdx.x;
  int dir = wg >> 6, b = wg & 63;
  int t = threadIdx.x;
  int j = t >> 1;            // unit 0..255
  int ks = t & 1;            // k-half

  // double-buffered h (fp16 pairs): region ks at ints [ks*72, ks*72+64), pad 8
  __shared__ unsigned int h_buf[2][144];

  const float* U = dir ? Ub : Uf;
  const float brh = (dir ? bbv : bfv)[768 + 512 + j];
  const unsigned short* gxd = gx + ((size_t)dir * 32768 + (size_t)b * 512) * 768;
  const int* xb = x + b * 512;
  float* outb = out + (size_t)b * 512 * 256;

  unsigned int uz[64], ur[64], uh[64];
  {
    const float* base = U + (size_t)(ks * 128) * 768 + j;
#pragma unroll
    for (int p = 0; p < 64; ++p) {
      const float* rp = base + (size_t)(2 * p) * 768;
      uz[p] = packf16(rp[0],   rp[768]);
      ur[p] = packf16(rp[256], rp[768 + 256]);
      uh[p] = packf16(rp[512], rp[768 + 512]);
    }
  }
  if (t < 144) h_buf[0][t] = 0u;
  __syncthreads();

  // prologue: preload step 0's gx + mask
  int tt0 = dir ? 511 : 0;
  {
  }
  const unsigned short* g0 = gxd + (size_t)tt0 * 768;
  float gz = bf2f(g0[j]), gr = bf2f(g0[256 + j]), gh = bf2f(g0[512 + j]);
  int xv = xb[tt0];

  float hj = 0.f;
  int cur = 0;
  for (int step = 0; step < 512; ++step) {
    int tcur = dir ? (511 - step) : step;
    // prefetch next step (latency hidden under dot loop)
    float gz_n = 0.f, gr_n = 0.f, gh_n = 0.f;
    int xv_n = 0;
    if (step < 511) {
      int tn = dir ? (510 - step) : (step + 1);
      const unsigned short* gn = gxd + (size_t)tn * 768;
      gz_n = bf2f(gn[j]); gr_n = bf2f(gn[256 + j]); gh_n = bf2f(gn[512 + j]);
      xv_n = xb[tn];
    }

    float az0 = 0.f, az1 = 0.f, ar0 = 0.f, ar1 = 0.f, ah0 = 0.f, ah1 = 0.f;
    const unsigned int* hb = &h_buf[cur][ks * 72];
#pragma unroll
    for (int c = 0; c < 16; ++c) {
      uint4 hv = *(const uint4*)&hb[c * 4];
      float& az = (c & 1) ? az1 : az0;
      float& ar = (c & 1) ? ar1 : ar0;
      float& ah = (c & 1) ? ah1 : ah0;
      az = dot2(uz[c * 4 + 0], hv.x, az);
      az = dot2(uz[c * 4 + 1], hv.y, az);
      az = dot2(uz[c * 4 + 2], hv.z, az);
      az = dot2(uz[c * 4 + 3], hv.w, az);
      ar = dot2(ur[c * 4 + 0], hv.x, ar);
      ar = dot2(ur[c * 4 + 1], hv.y, ar);
      ar = dot2(ur[c * 4 + 2], hv.z, ar);
      ar = dot2(ur[c * 4 + 3], hv.w, ar);
      ah = dot2(uh[c * 4 + 0], hv.x, ah);
      ah = dot2(uh[c * 4 + 1], hv.y, ah);
      ah = dot2(uh[c * 4 + 2], hv.z, ah);
      ah = dot2(uh[c * 4 + 3], hv.w, ah);
    }
    float az = az0 + az1; az += __shfl_xor(az, 1);
    float ar = ar0 + ar1; ar += __shfl_xor(ar, 1);
    float ah = ah0 + ah1; ah += __shfl_xor(ah, 1);

    float z = 1.f / (1.f + __expf(-(gz + az)));
    float r = 1.f / (1.f + __expf(-(gr + ar)));
    float e2 = __expf(2.f * (gh + r * (ah + brh)));
    float hh = (e2 - 1.f) / (e2 + 1.f);
    float hn = z * hj + (1.f - z) * hh;
    hn = (xv == 0) ? hj : hn;                       // masked: carry

    float hpart = __shfl_xor(hn, 2);                // partner unit's hn
    if ((t & 3) == 0) {
      int m = t >> 2;                               // h-pair index 0..127
      h_buf[cur ^ 1][(m >> 6) * 72 + (m & 63)] = packf16(hn, hpart);
    }
    __syncthreads();                                // single barrier per step

    if (ks == 0) atomicAdd(&outb[(size_t)tcur * 256 + j], hn);
    hj = hn; gz = gz_n; gr = gr_n; gh = gh_n; xv = xv_n;
    cur ^= 1;
  }
}

// ---------------------------------------------------------------------------
extern "C" void kernel_launch(void* const* d_in, const int* in_sizes, int n_in,
                              void* d_out, int out_size, void* d_ws, size_t ws_size,
                              hipStream_t stream) {
  const int*   x   = (const int*)d_in[0];
  const float* emb = (const float*)d_in[1];
  const float* Wf  = (const float*)d_in[2];
  const float* Uf  = (const float*)d_in[3];
  const float* bf_ = (const float*)d_in[4];
  const float* Wb  = (const float*)d_in[5];
  const float* Ub  = (const float*)d_in[6];
  const float* bb_ = (const float*)d_in[7];
  float* out = (float*)d_out;

  unsigned short* gxp = (unsigned short*)d_ws;                          // 100.7 MB
  unsigned short* Wtb = (unsigned short*)((char*)d_ws + 100663296);     // 768 KB

  hipMemsetAsync(d_out, 0, (size_t)out_size * sizeof(float), stream);

  wt_prep_kernel<<<1536, 256, 0, stream>>>(Wf, Wb, Wtb);
  gx_mfma_kernel<<<dim3(256, 12), 256, 0, stream>>>(x, emb, Wtb, bf_, bb_, gxp);
  gru_kernel<<<128, 512, 0, stream>>>(Uf, Ub, gxp, x, bf_, bb_, out);
}